// Round 5
// baseline (808.016 us; speedup 1.0000x reference)
//
#include <hip/hip_runtime.h>
#include <math.h>

#define NB    16      // batch
#define CDIM  256
#define COUT  144     // 64 q + 16 k + 64 v
#define MPIX  4096    // 64*64
#define SCOPE 23
#define PADH  11
#define BNEPS 1e-5f

typedef __attribute__((ext_vector_type(4))) float f32x4;
typedef __attribute__((ext_vector_type(8))) short s16x8;

__device__ __forceinline__ unsigned short f2bf(float f) {
    unsigned u = __builtin_bit_cast(unsigned, f);
    unsigned r = (u + 0x7FFFu + ((u >> 16) & 1u)) >> 16;
    return (unsigned short)r;
}
__device__ __forceinline__ float bf2f(unsigned short s) {
    unsigned u = ((unsigned)s) << 16;
    return __builtin_bit_cast(float, u);
}

// ---------------- K1: qkv = w_qkv @ x  (per batch: 144x256 @ 256x4096) ----------------
__global__ void __launch_bounds__(256) gemm_qkv(const float* __restrict__ x,
                                                const float* __restrict__ w,
                                                float* __restrict__ qkv) {
    __shared__ float xs[32][256];
    __shared__ float wsb[48][33];
    int mt = blockIdx.x, ot = blockIdx.y, b = blockIdx.z;
    int m0 = mt * 256, o0 = ot * 48;
    int tid = threadIdx.x;
    int to = tid >> 6;
    int tm = tid & 63;
    float acc[12][4];
#pragma unroll
    for (int i = 0; i < 12; i++)
#pragma unroll
        for (int j = 0; j < 4; j++) acc[i][j] = 0.f;

    const float* xb = x + (size_t)b * CDIM * MPIX;
    for (int k0 = 0; k0 < CDIM; k0 += 32) {
        __syncthreads();
#pragma unroll
        for (int i = 0; i < 32; i++)
            xs[i][tid] = xb[(size_t)(k0 + i) * MPIX + m0 + tid];
#pragma unroll
        for (int i = 0; i < 6; i++) {
            int idx = i * 256 + tid;
            int o = idx >> 5, r = idx & 31;
            wsb[o][r] = w[(size_t)(o0 + o) * CDIM + k0 + r];
        }
        __syncthreads();
#pragma unroll 4
        for (int r = 0; r < 32; r++) {
            float4 xv = *(const float4*)&xs[r][tm * 4];
#pragma unroll
            for (int i = 0; i < 12; i++) {
                float wv = wsb[to * 12 + i][r];
                acc[i][0] = fmaf(wv, xv.x, acc[i][0]);
                acc[i][1] = fmaf(wv, xv.y, acc[i][1]);
                acc[i][2] = fmaf(wv, xv.z, acc[i][2]);
                acc[i][3] = fmaf(wv, xv.w, acc[i][3]);
            }
        }
    }
#pragma unroll
    for (int i = 0; i < 12; i++) {
        float4 v = make_float4(acc[i][0], acc[i][1], acc[i][2], acc[i][3]);
        *(float4*)&qkv[((size_t)b * COUT + o0 + to * 12 + i) * MPIX + m0 + tm * 4] = v;
    }
}

// ---------------- K2: BN partial sums per (channel, batch) ----------------
__global__ void stats_partial(const float* __restrict__ qkv, float* __restrict__ part) {
    int ch = blockIdx.x, b = blockIdx.y;
    int o = (ch < 64) ? ch : (80 + ch - 64);
    const float* row = qkv + ((size_t)b * COUT + o) * MPIX;
    int tid = threadIdx.x;
    float s = 0.f, s2 = 0.f;
    for (int i = tid; i < MPIX; i += 256) {
        float v = row[i];
        s += v;
        s2 = fmaf(v, v, s2);
    }
#pragma unroll
    for (int off = 32; off > 0; off >>= 1) {
        s += __shfl_down(s, off);
        s2 += __shfl_down(s2, off);
    }
    __shared__ float red[8];
    int wid = tid >> 6, lane = tid & 63;
    if (lane == 0) { red[wid * 2] = s; red[wid * 2 + 1] = s2; }
    __syncthreads();
    if (tid == 0) {
        float ts = 0.f, ts2 = 0.f;
#pragma unroll
        for (int w2 = 0; w2 < 4; w2++) { ts += red[w2 * 2]; ts2 += red[w2 * 2 + 1]; }
        part[(size_t)(ch * 16 + b) * 2 + 0] = ts;
        part[(size_t)(ch * 16 + b) * 2 + 1] = ts2;
    }
}

// ---------------- K3: finalize scale/shift ----------------
__global__ void stats_finalize(const float* __restrict__ part,
                               const float* __restrict__ gq, const float* __restrict__ bq,
                               const float* __restrict__ gv, const float* __restrict__ bv,
                               float* __restrict__ ascale, float* __restrict__ dshift) {
    int ch = threadIdx.x;
    if (ch >= 128) return;
    float s = 0.f, s2 = 0.f;
    for (int b = 0; b < 16; b++) {
        s += part[(size_t)(ch * 16 + b) * 2 + 0];
        s2 += part[(size_t)(ch * 16 + b) * 2 + 1];
    }
    const float invN = 1.0f / 65536.0f;
    float mean = s * invN;
    float var = s2 * invN - mean * mean;
    float g = (ch < 64) ? gq[ch] : gv[ch - 64];
    float be = (ch < 64) ? bq[ch] : bv[ch - 64];
    float a = g * rsqrtf(var + BNEPS);
    ascale[ch] = a;
    dshift[ch] = be - mean * a;
}

// ---------------- K4: softmax over m for each (b, kc) ----------------
__global__ void softmax_k(const float* __restrict__ qkv, float* __restrict__ p) {
    int bk = blockIdx.x;
    int b = bk >> 4, kc = bk & 15;
    const float* row = qkv + ((size_t)b * COUT + 64 + kc) * MPIX;
    int tid = threadIdx.x;
    float v[16];
    float mx = -INFINITY;
#pragma unroll
    for (int i = 0; i < 16; i++) {
        v[i] = row[tid + i * 256];
        mx = fmaxf(mx, v[i]);
    }
#pragma unroll
    for (int off = 32; off > 0; off >>= 1) mx = fmaxf(mx, __shfl_down(mx, off));
    __shared__ float redm[4];
    __shared__ float bm;
    int wid = tid >> 6, lane = tid & 63;
    if (lane == 0) redm[wid] = mx;
    __syncthreads();
    if (tid == 0) bm = fmaxf(fmaxf(redm[0], redm[1]), fmaxf(redm[2], redm[3]));
    __syncthreads();
    mx = bm;
    float s = 0.f;
#pragma unroll
    for (int i = 0; i < 16; i++) {
        v[i] = expf(v[i] - mx);
        s += v[i];
    }
#pragma unroll
    for (int off = 32; off > 0; off >>= 1) s += __shfl_down(s, off);
    __shared__ float reds[4];
    __shared__ float bs;
    if (lane == 0) reds[wid] = s;
    __syncthreads();
    if (tid == 0) bs = reds[0] + reds[1] + reds[2] + reds[3];
    __syncthreads();
    float r = 1.0f / bs;
    float* prow = p + ((size_t)b * 16 + kc) * MPIX;
#pragma unroll
    for (int i = 0; i < 16; i++) prow[tid + i * 256] = v[i] * r;
}

// ---------------- K5: content lambda partials ----------------
__global__ void cl_partial(const float* __restrict__ qkv, const float* __restrict__ p,
                           const float* __restrict__ ascale, const float* __restrict__ dshift,
                           float* __restrict__ clpart) {
    __shared__ float vsT[128][65];
    int mc = blockIdx.x, b = blockIdx.y;
    int m0 = mc * 256;
    int tid = threadIdx.x;
    int vc = tid & 63, kg = tid >> 6;
    float acc[4] = {0.f, 0.f, 0.f, 0.f};
    for (int half = 0; half < 2; half++) {
        int mh = m0 + half * 128;
        __syncthreads();
        for (int i = tid; i < 64 * 128; i += 256) {
            int r = i >> 7, c = i & 127;
            vsT[c][r] = fmaf(ascale[64 + r], qkv[((size_t)b * COUT + 80 + r) * MPIX + mh + c],
                             dshift[64 + r]);
        }
        __syncthreads();
        for (int mm = 0; mm < 128; mm++) {
            float vv = vsT[mm][vc];
#pragma unroll
            for (int i = 0; i < 4; i++) {
                int kc = kg * 4 + i;
                acc[i] = fmaf(p[((size_t)b * 16 + kc) * MPIX + mh + mm], vv, acc[i]);
            }
        }
    }
#pragma unroll
    for (int i = 0; i < 4; i++) {
        int kc = kg * 4 + i;
        clpart[(((size_t)b * 16 + mc) * 16 + kc) * 64 + vc] = acc[i];
    }
}

__global__ void cl_reduce(const float* __restrict__ clpart, float* __restrict__ cl) {
    int b = blockIdx.x;
    for (int o = threadIdx.x; o < 1024; o += 256) {
        float s = 0.f;
        for (int mc = 0; mc < 16; mc++)
            s += clpart[((size_t)b * 16 + mc) * 1024 + o];
        cl[(size_t)b * 1024 + o] = s;
    }
}

// ---------------- K6: apply BN to q channels in-place ----------------
__global__ void bn_q(float* __restrict__ qkv, const float* __restrict__ ascale,
                     const float* __restrict__ dshift) {
    int c = blockIdx.x, b = blockIdx.y;
    float a = ascale[c], d = dshift[c];
    float4* p = (float4*)(qkv + ((size_t)b * COUT + c) * MPIX);
    for (int i = threadIdx.x; i < 1024; i += 256) {
        float4 v = p[i];
        v.x = fmaf(a, v.x, d);
        v.y = fmaf(a, v.y, d);
        v.z = fmaf(a, v.z, d);
        v.w = fmaf(a, v.w, d);
        p[i] = v;
    }
}

// ---------------- K7: build MFMA A-fragments of lconv weights (bf16 hi/lo split) --------
__global__ void wfrag_prep(const float* __restrict__ wl, short* __restrict__ wfrag) {
    int i = blockIdx.x * 256 + threadIdx.x;
    if (i >= 23 * 2 * 64 * 8) return;
    int j = i & 7, l = (i >> 3) & 63, pass = (i >> 9) & 1, dy = i >> 10;
    int k = l & 15, t = ((l >> 4) << 3) + j;
    float w = (t < SCOPE) ? wl[k * 529 + dy * 23 + t] : 0.f;
    unsigned short hi = f2bf(w);
    unsigned short res = pass ? f2bf(w - bf2f(hi)) : hi;
    wfrag[i] = (short)res;
}

// ---------------- K8: fused MFMA conv + lambda epilogue (row-fragment reuse) ----------
// grid (64 vc, 16 b), block 256 (4 waves). Per wave per gg: 4 output rows x 64 px.
// Iterate image rows r=0..25; per row load 4 xt B-fragments ONCE, fire up to
// 4 ty x 2 (hi/lo) MFMAs each with rolling 4-deep weight window (slot = dy&3).
#define SPW 88
__global__ void __launch_bounds__(256, 3) lambda_main(
    const float* __restrict__ qkv, const float* __restrict__ ascale,
    const float* __restrict__ dshift, const float* __restrict__ cl,
    const short* __restrict__ wfrag, const float* __restrict__ bl,
    float* __restrict__ out) {
    __shared__ unsigned spack[86 * SPW + 8];
    __shared__ float sck[16];

    int vc = blockIdx.x, b = blockIdx.y;
    int tid = threadIdx.x;

    if (tid < 16) sck[tid] = cl[((size_t)b * 16 + tid) * 64 + vc] + bl[tid];

    float av = ascale[64 + vc], dv = dshift[64 + vc];
    const float* vrow = qkv + ((size_t)b * COUT + 80 + vc) * MPIX;
    for (int i = tid; i < 86 * SPW; i += 256) {
        int y = i / SPW, e = i - y * SPW;
        int iy = y - PADH;
        float f0 = 0.f, f1 = 0.f;
        if ((unsigned)iy < 64u) {
            int ix0 = e - PADH, ix1 = e - PADH + 1;
            if ((unsigned)ix0 < 64u) f0 = fmaf(av, vrow[iy * 64 + ix0], dv);
            if ((unsigned)ix1 < 64u) f1 = fmaf(av, vrow[iy * 64 + ix1], dv);
        }
        spack[i] = (unsigned)f2bf(f0) | ((unsigned)f2bf(f1) << 16);
    }
    if (tid < 8) spack[86 * SPW + tid] = 0u;
    __syncthreads();

    int lane = tid & 63;
    int wv = tid >> 6;
    int px = lane & 15;
    int kg = lane >> 4;
    const s16x8* wf = (const s16x8*)wfrag;

    const float* qslab = qkv + (size_t)b * COUT * MPIX;
    float* ob = out + (size_t)b * 256 * MPIX;

    float sck_l[4];
#pragma unroll
    for (int r = 0; r < 4; r++) sck_l[r] = sck[kg * 4 + r];

#pragma unroll 1
    for (int gg = 0; gg < 4; gg++) {
        int y0 = (gg * 4 + wv) * 4;
        f32x4 acc[16];
#pragma unroll
        for (int t = 0; t < 16; t++) acc[t] = 0.f;

        const unsigned* rowbase = &spack[y0 * SPW + px + kg * 8];
        s16x8 wa[4], wb[4];   // rolling window, slot = dy & 3 (static after unroll)

#pragma unroll
        for (int r = 0; r < 26; r++) {
            if (r <= 22) {
                wa[r & 3] = wf[(r * 2 + 0) * 64 + lane];
                wb[r & 3] = wf[(r * 2 + 1) * 64 + lane];
            }
            s16x8 bfr[4];
#pragma unroll
            for (int xt = 0; xt < 4; xt++) {
                const unsigned* p = rowbase + r * SPW + xt * 16;
                int4 bi = make_int4(p[0], p[2], p[4], p[6]);  // 2x ds_read2_b32
                bfr[xt] = __builtin_bit_cast(s16x8, bi);
            }
#pragma unroll
            for (int ty = 0; ty < 4; ty++) {
                int dy = r - ty;
                if (dy >= 0 && dy <= 22) {
#pragma unroll
                    for (int xt = 0; xt < 4; xt++) {
                        int t = ty * 4 + xt;
                        acc[t] = __builtin_amdgcn_mfma_f32_16x16x32_bf16(wa[dy & 3], bfr[xt], acc[t], 0, 0, 0);
                        acc[t] = __builtin_amdgcn_mfma_f32_16x16x32_bf16(wb[dy & 3], bfr[xt], acc[t], 0, 0, 0);
                    }
                }
            }
        }

        // epilogue: lane holds pl[kf = kg*4+r][px] for its 16-px tile
#pragma unroll
        for (int t = 0; t < 16; t++) {
            int ty = t >> 2, xt = t & 3;
            int m0 = (y0 + ty) * 64 + xt * 16;
            float lam[4];
#pragma unroll
            for (int r = 0; r < 4; r++) lam[r] = acc[t][r] + sck_l[r];
            float po[4] = {0.f, 0.f, 0.f, 0.f};
#pragma unroll
            for (int i = 0; i < 16; i++) {
                float qv = qslab[(size_t)(kg * 16 + i) * MPIX + m0 + px];
                po[i & 3] = fmaf(qv, lam[i >> 2], po[i & 3]);
            }
#pragma unroll
            for (int n = 0; n < 4; n++) {
                po[n] += __shfl_xor(po[n], 16);
                po[n] += __shfl_xor(po[n], 32);
            }
            float sv = (kg == 0) ? po[0] : (kg == 1) ? po[1] : (kg == 2) ? po[2] : po[3];
            ob[(size_t)(kg * 64 + vc) * MPIX + m0 + px] = sv;
        }
    }
}

// ---------------- launch ----------------
extern "C" void kernel_launch(void* const* d_in, const int* in_sizes, int n_in,
                              void* d_out, int out_size, void* d_ws, size_t ws_size,
                              hipStream_t stream) {
    const float* x      = (const float*)d_in[0];
    const float* w_qkv  = (const float*)d_in[1];
    const float* gq     = (const float*)d_in[2];
    const float* bq     = (const float*)d_in[3];
    const float* gv     = (const float*)d_in[4];
    const float* bv     = (const float*)d_in[5];
    const float* wl     = (const float*)d_in[6];
    const float* bl     = (const float*)d_in[7];
    float* out = (float*)d_out;

    float* ws     = (float*)d_ws;
    float* qkv    = ws;                    // 16*144*4096 = 9,437,184
    float* p      = qkv + 9437184;         // 1,048,576
    float* part   = p + 1048576;           // 4,096
    float* ascale = part + 4096;           // 128
    float* dshift = ascale + 128;          // 128
    float* clpart = dshift + 128;          // 262,144
    float* clb    = clpart + 262144;       // 16,384
    short* wfrag  = (short*)(clb + 16384); // 23552 halfs

    gemm_qkv<<<dim3(16, 3, 16), 256, 0, stream>>>(x, w_qkv, qkv);
    stats_partial<<<dim3(128, 16), 256, 0, stream>>>(qkv, part);
    stats_finalize<<<1, 128, 0, stream>>>(part, gq, bq, gv, bv, ascale, dshift);
    softmax_k<<<256, 256, 0, stream>>>(qkv, p);
    cl_partial<<<dim3(16, 16), 256, 0, stream>>>(qkv, p, ascale, dshift, clpart);
    cl_reduce<<<16, 256, 0, stream>>>(clpart, clb);
    bn_q<<<dim3(64, 16), 256, 0, stream>>>(qkv, ascale, dshift);
    wfrag_prep<<<92, 256, 0, stream>>>(wl, wfrag);
    lambda_main<<<dim3(64, 16), 256, 0, stream>>>(qkv, ascale, dshift, clb, wfrag, bl, out);
}

// Round 6
// 306.496 us; speedup vs baseline: 2.6363x; 2.6363x over previous
//
#include <hip/hip_runtime.h>
#include <math.h>

#define NB    16      // batch
#define CDIM  256
#define COUT  144     // 64 q + 16 k + 64 v
#define MPIX  4096    // 64*64
#define SCOPE 23
#define PADH  11
#define BNEPS 1e-5f

typedef __attribute__((ext_vector_type(4))) float f32x4;
typedef __attribute__((ext_vector_type(8))) short s16x8;

__device__ __forceinline__ unsigned short f2bf(float f) {
    unsigned u = __builtin_bit_cast(unsigned, f);
    unsigned r = (u + 0x7FFFu + ((u >> 16) & 1u)) >> 16;
    return (unsigned short)r;
}
__device__ __forceinline__ float bf2f(unsigned short s) {
    unsigned u = ((unsigned)s) << 16;
    return __builtin_bit_cast(float, u);
}

// ---------------- K1: qkv = w_qkv @ x  (per batch: 144x256 @ 256x4096) ----------------
__global__ void __launch_bounds__(256) gemm_qkv(const float* __restrict__ x,
                                                const float* __restrict__ w,
                                                float* __restrict__ qkv) {
    __shared__ float xs[32][256];
    __shared__ float wsb[48][33];
    int mt = blockIdx.x, ot = blockIdx.y, b = blockIdx.z;
    int m0 = mt * 256, o0 = ot * 48;
    int tid = threadIdx.x;
    int to = tid >> 6;
    int tm = tid & 63;
    float acc[12][4];
#pragma unroll
    for (int i = 0; i < 12; i++)
#pragma unroll
        for (int j = 0; j < 4; j++) acc[i][j] = 0.f;

    const float* xb = x + (size_t)b * CDIM * MPIX;
    for (int k0 = 0; k0 < CDIM; k0 += 32) {
        __syncthreads();
#pragma unroll
        for (int i = 0; i < 32; i++)
            xs[i][tid] = xb[(size_t)(k0 + i) * MPIX + m0 + tid];
#pragma unroll
        for (int i = 0; i < 6; i++) {
            int idx = i * 256 + tid;
            int o = idx >> 5, r = idx & 31;
            wsb[o][r] = w[(size_t)(o0 + o) * CDIM + k0 + r];
        }
        __syncthreads();
#pragma unroll 4
        for (int r = 0; r < 32; r++) {
            float4 xv = *(const float4*)&xs[r][tm * 4];
#pragma unroll
            for (int i = 0; i < 12; i++) {
                float wv = wsb[to * 12 + i][r];
                acc[i][0] = fmaf(wv, xv.x, acc[i][0]);
                acc[i][1] = fmaf(wv, xv.y, acc[i][1]);
                acc[i][2] = fmaf(wv, xv.z, acc[i][2]);
                acc[i][3] = fmaf(wv, xv.w, acc[i][3]);
            }
        }
    }
#pragma unroll
    for (int i = 0; i < 12; i++) {
        float4 v = make_float4(acc[i][0], acc[i][1], acc[i][2], acc[i][3]);
        *(float4*)&qkv[((size_t)b * COUT + o0 + to * 12 + i) * MPIX + m0 + tm * 4] = v;
    }
}

// ---------------- K2: BN partial sums per (channel, batch) ----------------
__global__ void stats_partial(const float* __restrict__ qkv, float* __restrict__ part) {
    int ch = blockIdx.x, b = blockIdx.y;
    int o = (ch < 64) ? ch : (80 + ch - 64);
    const float* row = qkv + ((size_t)b * COUT + o) * MPIX;
    int tid = threadIdx.x;
    float s = 0.f, s2 = 0.f;
    for (int i = tid; i < MPIX; i += 256) {
        float v = row[i];
        s += v;
        s2 = fmaf(v, v, s2);
    }
#pragma unroll
    for (int off = 32; off > 0; off >>= 1) {
        s += __shfl_down(s, off);
        s2 += __shfl_down(s2, off);
    }
    __shared__ float red[8];
    int wid = tid >> 6, lane = tid & 63;
    if (lane == 0) { red[wid * 2] = s; red[wid * 2 + 1] = s2; }
    __syncthreads();
    if (tid == 0) {
        float ts = 0.f, ts2 = 0.f;
#pragma unroll
        for (int w2 = 0; w2 < 4; w2++) { ts += red[w2 * 2]; ts2 += red[w2 * 2 + 1]; }
        part[(size_t)(ch * 16 + b) * 2 + 0] = ts;
        part[(size_t)(ch * 16 + b) * 2 + 1] = ts2;
    }
}

// ---------------- K3: finalize scale/shift ----------------
__global__ void stats_finalize(const float* __restrict__ part,
                               const float* __restrict__ gq, const float* __restrict__ bq,
                               const float* __restrict__ gv, const float* __restrict__ bv,
                               float* __restrict__ ascale, float* __restrict__ dshift) {
    int ch = threadIdx.x;
    if (ch >= 128) return;
    float s = 0.f, s2 = 0.f;
    for (int b = 0; b < 16; b++) {
        s += part[(size_t)(ch * 16 + b) * 2 + 0];
        s2 += part[(size_t)(ch * 16 + b) * 2 + 1];
    }
    const float invN = 1.0f / 65536.0f;
    float mean = s * invN;
    float var = s2 * invN - mean * mean;
    float g = (ch < 64) ? gq[ch] : gv[ch - 64];
    float be = (ch < 64) ? bq[ch] : bv[ch - 64];
    float a = g * rsqrtf(var + BNEPS);
    ascale[ch] = a;
    dshift[ch] = be - mean * a;
}

// ---------------- K4: softmax over m for each (b, kc) ----------------
__global__ void softmax_k(const float* __restrict__ qkv, float* __restrict__ p) {
    int bk = blockIdx.x;
    int b = bk >> 4, kc = bk & 15;
    const float* row = qkv + ((size_t)b * COUT + 64 + kc) * MPIX;
    int tid = threadIdx.x;
    float v[16];
    float mx = -INFINITY;
#pragma unroll
    for (int i = 0; i < 16; i++) {
        v[i] = row[tid + i * 256];
        mx = fmaxf(mx, v[i]);
    }
#pragma unroll
    for (int off = 32; off > 0; off >>= 1) mx = fmaxf(mx, __shfl_down(mx, off));
    __shared__ float redm[4];
    __shared__ float bm;
    int wid = tid >> 6, lane = tid & 63;
    if (lane == 0) redm[wid] = mx;
    __syncthreads();
    if (tid == 0) bm = fmaxf(fmaxf(redm[0], redm[1]), fmaxf(redm[2], redm[3]));
    __syncthreads();
    mx = bm;
    float s = 0.f;
#pragma unroll
    for (int i = 0; i < 16; i++) {
        v[i] = expf(v[i] - mx);
        s += v[i];
    }
#pragma unroll
    for (int off = 32; off > 0; off >>= 1) s += __shfl_down(s, off);
    __shared__ float reds[4];
    __shared__ float bs;
    if (lane == 0) reds[wid] = s;
    __syncthreads();
    if (tid == 0) bs = reds[0] + reds[1] + reds[2] + reds[3];
    __syncthreads();
    float r = 1.0f / bs;
    float* prow = p + ((size_t)b * 16 + kc) * MPIX;
#pragma unroll
    for (int i = 0; i < 16; i++) prow[tid + i * 256] = v[i] * r;
}

// ---------------- K5: content lambda partials ----------------
__global__ void cl_partial(const float* __restrict__ qkv, const float* __restrict__ p,
                           const float* __restrict__ ascale, const float* __restrict__ dshift,
                           float* __restrict__ clpart) {
    __shared__ float vsT[128][65];
    int mc = blockIdx.x, b = blockIdx.y;
    int m0 = mc * 256;
    int tid = threadIdx.x;
    int vc = tid & 63, kg = tid >> 6;
    float acc[4] = {0.f, 0.f, 0.f, 0.f};
    for (int half = 0; half < 2; half++) {
        int mh = m0 + half * 128;
        __syncthreads();
        for (int i = tid; i < 64 * 128; i += 256) {
            int r = i >> 7, c = i & 127;
            vsT[c][r] = fmaf(ascale[64 + r], qkv[((size_t)b * COUT + 80 + r) * MPIX + mh + c],
                             dshift[64 + r]);
        }
        __syncthreads();
        for (int mm = 0; mm < 128; mm++) {
            float vv = vsT[mm][vc];
#pragma unroll
            for (int i = 0; i < 4; i++) {
                int kc = kg * 4 + i;
                acc[i] = fmaf(p[((size_t)b * 16 + kc) * MPIX + mh + mm], vv, acc[i]);
            }
        }
    }
#pragma unroll
    for (int i = 0; i < 4; i++) {
        int kc = kg * 4 + i;
        clpart[(((size_t)b * 16 + mc) * 16 + kc) * 64 + vc] = acc[i];
    }
}

__global__ void cl_reduce(const float* __restrict__ clpart, float* __restrict__ cl) {
    int b = blockIdx.x;
    for (int o = threadIdx.x; o < 1024; o += 256) {
        float s = 0.f;
        for (int mc = 0; mc < 16; mc++)
            s += clpart[((size_t)b * 16 + mc) * 1024 + o];
        cl[(size_t)b * 1024 + o] = s;
    }
}

// ---------------- K6: apply BN to q channels in-place ----------------
__global__ void bn_q(float* __restrict__ qkv, const float* __restrict__ ascale,
                     const float* __restrict__ dshift) {
    int c = blockIdx.x, b = blockIdx.y;
    float a = ascale[c], d = dshift[c];
    float4* p = (float4*)(qkv + ((size_t)b * COUT + c) * MPIX);
    for (int i = threadIdx.x; i < 1024; i += 256) {
        float4 v = p[i];
        v.x = fmaf(a, v.x, d);
        v.y = fmaf(a, v.y, d);
        v.z = fmaf(a, v.z, d);
        v.w = fmaf(a, v.w, d);
        p[i] = v;
    }
}

// ---------------- K7: build MFMA A-fragments of lconv weights (bf16 hi/lo split) --------
__global__ void wfrag_prep(const float* __restrict__ wl, short* __restrict__ wfrag) {
    int i = blockIdx.x * 256 + threadIdx.x;
    if (i >= 23 * 2 * 64 * 8) return;
    int j = i & 7, l = (i >> 3) & 63, pass = (i >> 9) & 1, dy = i >> 10;
    int k = l & 15, t = ((l >> 4) << 3) + j;
    float w = (t < SCOPE) ? wl[k * 529 + dy * 23 + t] : 0.f;
    unsigned short hi = f2bf(w);
    unsigned short res = pass ? f2bf(w - bf2f(hi)) : hi;
    wfrag[i] = (short)res;
}

// ---------------- K8: fused MFMA conv + lambda epilogue ----------------
// grid (64 vc, 16 b), block 256 (4 waves). Per wave per gg: 4 output rows x 64 px,
// split into 2 xt-halves (acc[8], 32 regs). dy-loop with 4-row sliding window
// (slot = row&3, static via 4-step macro in an unroll-1 outer loop) and
// ping-pong weight prefetch (wpp[j&1]).
#define SPW 88
#define LD_FRAG(P) __builtin_bit_cast(s16x8, make_int4((P)[0], (P)[2], (P)[4], (P)[6]))
#define STEP(DY, J) do {                                                        \
    int dyn_ = ((DY) < 22) ? (DY) + 1 : 22;                                     \
    wpp[((J) + 1) & 1][0] = wf[(dyn_ * 2 + 0) * 64 + lane];                     \
    wpp[((J) + 1) & 1][1] = wf[(dyn_ * 2 + 1) * 64 + lane];                     \
    const unsigned* pnew_ = xbase + ((DY) + 3) * SPW;                           \
    rw[((J) + 3) & 3][0] = LD_FRAG(pnew_);                                      \
    rw[((J) + 3) & 3][1] = LD_FRAG(pnew_ + 16);                                 \
    _Pragma("unroll")                                                           \
    for (int ty_ = 0; ty_ < 4; ty_++) {                                         \
      _Pragma("unroll")                                                         \
      for (int x2_ = 0; x2_ < 2; x2_++) {                                       \
        int t_ = ty_ * 2 + x2_;                                                 \
        acc[t_] = __builtin_amdgcn_mfma_f32_16x16x32_bf16(                      \
            wpp[(J) & 1][0], rw[((J) + ty_) & 3][x2_], acc[t_], 0, 0, 0);       \
        acc[t_] = __builtin_amdgcn_mfma_f32_16x16x32_bf16(                      \
            wpp[(J) & 1][1], rw[((J) + ty_) & 3][x2_], acc[t_], 0, 0, 0);       \
      }                                                                         \
    }                                                                           \
  } while (0)

__global__ void __launch_bounds__(256, 4) lambda_main(
    const float* __restrict__ qkv, const float* __restrict__ ascale,
    const float* __restrict__ dshift, const float* __restrict__ cl,
    const short* __restrict__ wfrag, const float* __restrict__ bl,
    float* __restrict__ out) {
    __shared__ unsigned spack[86 * SPW + 8];
    __shared__ float sck[16];

    int vc = blockIdx.x, b = blockIdx.y;
    int tid = threadIdx.x;

    if (tid < 16) sck[tid] = cl[((size_t)b * 16 + tid) * 64 + vc] + bl[tid];

    float av = ascale[64 + vc], dv = dshift[64 + vc];
    const float* vrow = qkv + ((size_t)b * COUT + 80 + vc) * MPIX;
    for (int i = tid; i < 86 * SPW; i += 256) {
        int y = i / SPW, e = i - y * SPW;
        int iy = y - PADH;
        float f0 = 0.f, f1 = 0.f;
        if ((unsigned)iy < 64u) {
            int ix0 = e - PADH, ix1 = e - PADH + 1;
            if ((unsigned)ix0 < 64u) f0 = fmaf(av, vrow[iy * 64 + ix0], dv);
            if ((unsigned)ix1 < 64u) f1 = fmaf(av, vrow[iy * 64 + ix1], dv);
        }
        spack[i] = (unsigned)f2bf(f0) | ((unsigned)f2bf(f1) << 16);
    }
    if (tid < 8) spack[86 * SPW + tid] = 0u;
    __syncthreads();

    int lane = tid & 63;
    int wv = tid >> 6;
    int px = lane & 15;
    int kg = lane >> 4;
    const s16x8* wf = (const s16x8*)wfrag;

    const float* qslab = qkv + (size_t)b * COUT * MPIX;
    float* ob = out + (size_t)b * 256 * MPIX;

    float sck_l[4];
#pragma unroll
    for (int r = 0; r < 4; r++) sck_l[r] = sck[kg * 4 + r];

#pragma unroll 1
    for (int gg = 0; gg < 4; gg++) {
        int y0 = (gg * 4 + wv) * 4;
        const unsigned* base = &spack[y0 * SPW + px + kg * 8];

#pragma unroll 1
        for (int xh = 0; xh < 2; xh++) {
            const unsigned* xbase = base + xh * 32;
            f32x4 acc[8];
#pragma unroll
            for (int t = 0; t < 8; t++) acc[t] = 0.f;

            s16x8 rw[4][2];   // sliding 4-row window, slot = row & 3
            s16x8 wpp[2][2];  // ping-pong weights [parity][hi/lo]
#pragma unroll
            for (int r0 = 0; r0 < 3; r0++) {
                const unsigned* p = xbase + r0 * SPW;
                rw[r0][0] = LD_FRAG(p);
                rw[r0][1] = LD_FRAG(p + 16);
            }
            wpp[0][0] = wf[0 * 64 + lane];
            wpp[0][1] = wf[1 * 64 + lane];

#pragma unroll 1
            for (int i4 = 0; i4 < 5; i4++) {
                int dyb = i4 * 4;
                STEP(dyb + 0, 0);
                STEP(dyb + 1, 1);
                STEP(dyb + 2, 2);
                STEP(dyb + 3, 3);
            }
            STEP(20, 0);
            STEP(21, 1);
            STEP(22, 2);

            // epilogue: lane holds pl[kf = kg*4+r][px] for its 8 tiles
#pragma unroll
            for (int t = 0; t < 8; t++) {
                int ty = t >> 1, x2 = t & 1;
                int m0 = (y0 + ty) * 64 + (xh * 2 + x2) * 16;
                float lam[4];
#pragma unroll
                for (int r = 0; r < 4; r++) lam[r] = acc[t][r] + sck_l[r];
                float po[4] = {0.f, 0.f, 0.f, 0.f};
#pragma unroll
                for (int i = 0; i < 16; i++) {
                    float qv = qslab[(size_t)(kg * 16 + i) * MPIX + m0 + px];
                    po[i & 3] = fmaf(qv, lam[i >> 2], po[i & 3]);
                }
#pragma unroll
                for (int n = 0; n < 4; n++) {
                    po[n] += __shfl_xor(po[n], 16);
                    po[n] += __shfl_xor(po[n], 32);
                }
                float sv = (kg == 0) ? po[0] : (kg == 1) ? po[1] : (kg == 2) ? po[2] : po[3];
                ob[(size_t)(kg * 64 + vc) * MPIX + m0 + px] = sv;
            }
        }
    }
}

// ---------------- launch ----------------
extern "C" void kernel_launch(void* const* d_in, const int* in_sizes, int n_in,
                              void* d_out, int out_size, void* d_ws, size_t ws_size,
                              hipStream_t stream) {
    const float* x      = (const float*)d_in[0];
    const float* w_qkv  = (const float*)d_in[1];
    const float* gq     = (const float*)d_in[2];
    const float* bq     = (const float*)d_in[3];
    const float* gv     = (const float*)d_in[4];
    const float* bv     = (const float*)d_in[5];
    const float* wl     = (const float*)d_in[6];
    const float* bl     = (const float*)d_in[7];
    float* out = (float*)d_out;

    float* ws     = (float*)d_ws;
    float* qkv    = ws;                    // 16*144*4096 = 9,437,184
    float* p      = qkv + 9437184;         // 1,048,576
    float* part   = p + 1048576;           // 4,096
    float* ascale = part + 4096;           // 128
    float* dshift = ascale + 128;          // 128
    float* clpart = dshift + 128;          // 262,144
    float* clb    = clpart + 262144;       // 16,384
    short* wfrag  = (short*)(clb + 16384); // 23552 halfs

    gemm_qkv<<<dim3(16, 3, 16), 256, 0, stream>>>(x, w_qkv, qkv);
    stats_partial<<<dim3(128, 16), 256, 0, stream>>>(qkv, part);
    stats_finalize<<<1, 128, 0, stream>>>(part, gq, bq, gv, bv, ascale, dshift);
    softmax_k<<<256, 256, 0, stream>>>(qkv, p);
    cl_partial<<<dim3(16, 16), 256, 0, stream>>>(qkv, p, ascale, dshift, clpart);
    cl_reduce<<<16, 256, 0, stream>>>(clpart, clb);
    bn_q<<<dim3(64, 16), 256, 0, stream>>>(qkv, ascale, dshift);
    wfrag_prep<<<92, 256, 0, stream>>>(wl, wfrag);
    lambda_main<<<dim3(64, 16), 256, 0, stream>>>(qkv, ascale, dshift, clb, wfrag, bl, out);
}

// Round 7
// 264.929 us; speedup vs baseline: 3.0499x; 1.1569x over previous
//
#include <hip/hip_runtime.h>
#include <math.h>

#define NB    16      // batch
#define CDIM  256
#define COUT  144     // 64 q + 16 k + 64 v
#define MPIX  4096    // 64*64
#define SCOPE 23
#define PADH  11
#define BNEPS 1e-5f

typedef __attribute__((ext_vector_type(4))) float f32x4;
typedef __attribute__((ext_vector_type(8))) short s16x8;

__device__ __forceinline__ unsigned short f2bf(float f) {
    unsigned u = __builtin_bit_cast(unsigned, f);
    unsigned r = (u + 0x7FFFu + ((u >> 16) & 1u)) >> 16;
    return (unsigned short)r;
}

// ---------------- K1: qkv = w_qkv @ x  (per batch: 144x256 @ 256x4096) ----------------
__global__ void __launch_bounds__(256) gemm_qkv(const float* __restrict__ x,
                                                const float* __restrict__ w,
                                                float* __restrict__ qkv) {
    __shared__ float xs[32][256];
    __shared__ float wsb[48][33];
    int mt = blockIdx.x, ot = blockIdx.y, b = blockIdx.z;
    int m0 = mt * 256, o0 = ot * 48;
    int tid = threadIdx.x;
    int to = tid >> 6;
    int tm = tid & 63;
    float acc[12][4];
#pragma unroll
    for (int i = 0; i < 12; i++)
#pragma unroll
        for (int j = 0; j < 4; j++) acc[i][j] = 0.f;

    const float* xb = x + (size_t)b * CDIM * MPIX;
    for (int k0 = 0; k0 < CDIM; k0 += 32) {
        __syncthreads();
#pragma unroll
        for (int i = 0; i < 32; i++)
            xs[i][tid] = xb[(size_t)(k0 + i) * MPIX + m0 + tid];
#pragma unroll
        for (int i = 0; i < 6; i++) {
            int idx = i * 256 + tid;
            int o = idx >> 5, r = idx & 31;
            wsb[o][r] = w[(size_t)(o0 + o) * CDIM + k0 + r];
        }
        __syncthreads();
#pragma unroll 4
        for (int r = 0; r < 32; r++) {
            float4 xv = *(const float4*)&xs[r][tm * 4];
#pragma unroll
            for (int i = 0; i < 12; i++) {
                float wv = wsb[to * 12 + i][r];
                acc[i][0] = fmaf(wv, xv.x, acc[i][0]);
                acc[i][1] = fmaf(wv, xv.y, acc[i][1]);
                acc[i][2] = fmaf(wv, xv.z, acc[i][2]);
                acc[i][3] = fmaf(wv, xv.w, acc[i][3]);
            }
        }
    }
#pragma unroll
    for (int i = 0; i < 12; i++) {
        float4 v = make_float4(acc[i][0], acc[i][1], acc[i][2], acc[i][3]);
        *(float4*)&qkv[((size_t)b * COUT + o0 + to * 12 + i) * MPIX + m0 + tm * 4] = v;
    }
}

// ---------------- K2: BN partial sums per (channel, batch) ----------------
__global__ void stats_partial(const float* __restrict__ qkv, float* __restrict__ part) {
    int ch = blockIdx.x, b = blockIdx.y;
    int o = (ch < 64) ? ch : (80 + ch - 64);
    const float* row = qkv + ((size_t)b * COUT + o) * MPIX;
    int tid = threadIdx.x;
    float s = 0.f, s2 = 0.f;
    for (int i = tid; i < MPIX; i += 256) {
        float v = row[i];
        s += v;
        s2 = fmaf(v, v, s2);
    }
#pragma unroll
    for (int off = 32; off > 0; off >>= 1) {
        s += __shfl_down(s, off);
        s2 += __shfl_down(s2, off);
    }
    __shared__ float red[8];
    int wid = tid >> 6, lane = tid & 63;
    if (lane == 0) { red[wid * 2] = s; red[wid * 2 + 1] = s2; }
    __syncthreads();
    if (tid == 0) {
        float ts = 0.f, ts2 = 0.f;
#pragma unroll
        for (int w2 = 0; w2 < 4; w2++) { ts += red[w2 * 2]; ts2 += red[w2 * 2 + 1]; }
        part[(size_t)(ch * 16 + b) * 2 + 0] = ts;
        part[(size_t)(ch * 16 + b) * 2 + 1] = ts2;
    }
}

// ---------------- K3: finalize scale/shift ----------------
__global__ void stats_finalize(const float* __restrict__ part,
                               const float* __restrict__ gq, const float* __restrict__ bq,
                               const float* __restrict__ gv, const float* __restrict__ bv,
                               float* __restrict__ ascale, float* __restrict__ dshift) {
    int ch = threadIdx.x;
    if (ch >= 128) return;
    float s = 0.f, s2 = 0.f;
    for (int b = 0; b < 16; b++) {
        s += part[(size_t)(ch * 16 + b) * 2 + 0];
        s2 += part[(size_t)(ch * 16 + b) * 2 + 1];
    }
    const float invN = 1.0f / 65536.0f;
    float mean = s * invN;
    float var = s2 * invN - mean * mean;
    float g = (ch < 64) ? gq[ch] : gv[ch - 64];
    float be = (ch < 64) ? bq[ch] : bv[ch - 64];
    float a = g * rsqrtf(var + BNEPS);
    ascale[ch] = a;
    dshift[ch] = be - mean * a;
}

// ---------------- K4: softmax over m for each (b, kc) ----------------
__global__ void softmax_k(const float* __restrict__ qkv, float* __restrict__ p) {
    int bk = blockIdx.x;
    int b = bk >> 4, kc = bk & 15;
    const float* row = qkv + ((size_t)b * COUT + 64 + kc) * MPIX;
    int tid = threadIdx.x;
    float v[16];
    float mx = -INFINITY;
#pragma unroll
    for (int i = 0; i < 16; i++) {
        v[i] = row[tid + i * 256];
        mx = fmaxf(mx, v[i]);
    }
#pragma unroll
    for (int off = 32; off > 0; off >>= 1) mx = fmaxf(mx, __shfl_down(mx, off));
    __shared__ float redm[4];
    __shared__ float bm;
    int wid = tid >> 6, lane = tid & 63;
    if (lane == 0) redm[wid] = mx;
    __syncthreads();
    if (tid == 0) bm = fmaxf(fmaxf(redm[0], redm[1]), fmaxf(redm[2], redm[3]));
    __syncthreads();
    mx = bm;
    float s = 0.f;
#pragma unroll
    for (int i = 0; i < 16; i++) {
        v[i] = expf(v[i] - mx);
        s += v[i];
    }
#pragma unroll
    for (int off = 32; off > 0; off >>= 1) s += __shfl_down(s, off);
    __shared__ float reds[4];
    __shared__ float bs;
    if (lane == 0) reds[wid] = s;
    __syncthreads();
    if (tid == 0) bs = reds[0] + reds[1] + reds[2] + reds[3];
    __syncthreads();
    float r = 1.0f / bs;
    float* prow = p + ((size_t)b * 16 + kc) * MPIX;
#pragma unroll
    for (int i = 0; i < 16; i++) prow[tid + i * 256] = v[i] * r;
}

// ---------------- K5: content lambda partials ----------------
__global__ void cl_partial(const float* __restrict__ qkv, const float* __restrict__ p,
                           const float* __restrict__ ascale, const float* __restrict__ dshift,
                           float* __restrict__ clpart) {
    __shared__ float vsT[128][65];
    int mc = blockIdx.x, b = blockIdx.y;
    int m0 = mc * 256;
    int tid = threadIdx.x;
    int vc = tid & 63, kg = tid >> 6;
    float acc[4] = {0.f, 0.f, 0.f, 0.f};
    for (int half = 0; half < 2; half++) {
        int mh = m0 + half * 128;
        __syncthreads();
        for (int i = tid; i < 64 * 128; i += 256) {
            int r = i >> 7, c = i & 127;
            vsT[c][r] = fmaf(ascale[64 + r], qkv[((size_t)b * COUT + 80 + r) * MPIX + mh + c],
                             dshift[64 + r]);
        }
        __syncthreads();
        for (int mm = 0; mm < 128; mm++) {
            float vv = vsT[mm][vc];
#pragma unroll
            for (int i = 0; i < 4; i++) {
                int kc = kg * 4 + i;
                acc[i] = fmaf(p[((size_t)b * 16 + kc) * MPIX + mh + mm], vv, acc[i]);
            }
        }
    }
#pragma unroll
    for (int i = 0; i < 4; i++) {
        int kc = kg * 4 + i;
        clpart[(((size_t)b * 16 + mc) * 16 + kc) * 64 + vc] = acc[i];
    }
}

__global__ void cl_reduce(const float* __restrict__ clpart, float* __restrict__ cl) {
    int b = blockIdx.x;
    for (int o = threadIdx.x; o < 1024; o += 256) {
        float s = 0.f;
        for (int mc = 0; mc < 16; mc++)
            s += clpart[((size_t)b * 16 + mc) * 1024 + o];
        cl[(size_t)b * 1024 + o] = s;
    }
}

// ---------------- K6: apply BN to q channels in-place ----------------
__global__ void bn_q(float* __restrict__ qkv, const float* __restrict__ ascale,
                     const float* __restrict__ dshift) {
    int c = blockIdx.x, b = blockIdx.y;
    float a = ascale[c], d = dshift[c];
    float4* p = (float4*)(qkv + ((size_t)b * COUT + c) * MPIX);
    for (int i = threadIdx.x; i < 1024; i += 256) {
        float4 v = p[i];
        v.x = fmaf(a, v.x, d);
        v.y = fmaf(a, v.y, d);
        v.z = fmaf(a, v.z, d);
        v.w = fmaf(a, v.w, d);
        p[i] = v;
    }
}

// ---------------- K7: build MFMA A-fragments of lconv weights (bf16 hi only) --------
// layout: wfrag[(dy*64 + lane)*8 + j], lane -> k = lane&15, tap = (lane>>4)*8 + j
__global__ void wfrag_prep(const float* __restrict__ wl, short* __restrict__ wfrag) {
    int i = blockIdx.x * 256 + threadIdx.x;
    if (i >= 23 * 64 * 8) return;
    int j = i & 7, l = (i >> 3) & 63, dy = i >> 9;
    int k = l & 15, t = ((l >> 4) << 3) + j;
    float w = (t < SCOPE) ? wl[k * 529 + dy * 23 + t] : 0.f;
    wfrag[i] = (short)f2bf(w);
}

// ---------------- K8: fused MFMA conv + lambda epilogue ----------------
// grid (64 vc, 16 b), block 256 (4 waves). Per wave per gg: 4 output rows x 64 px,
// split into 2 xt-halves (acc[8]). dy-loop, single bf16 weight pass, ring-8 weight
// prefetch from global (7-step = ~270 cyc cover), 4-row sliding window (rows loaded
// at step top; ty=3 MFMAs last in source order).
#define SPW 88
#define LD_FRAG(P) __builtin_bit_cast(s16x8, make_int4((P)[0], (P)[2], (P)[4], (P)[6]))
#define STEP(DY, J) do {                                                        \
    const unsigned* pnew_ = xbase + ((DY) + 3) * SPW;                           \
    rw[((J) + 3) & 3][0] = LD_FRAG(pnew_);                                      \
    rw[((J) + 3) & 3][1] = LD_FRAG(pnew_ + 16);                                 \
    int dyn_ = ((DY) + 7 < 22) ? (DY) + 7 : 22;                                 \
    wr[((J) + 7) & 7] = wf[dyn_ * 64 + lane];                                   \
    _Pragma("unroll")                                                           \
    for (int ty_ = 0; ty_ < 4; ty_++) {                                         \
      _Pragma("unroll")                                                         \
      for (int x2_ = 0; x2_ < 2; x2_++) {                                       \
        int t_ = ty_ * 2 + x2_;                                                 \
        acc[t_] = __builtin_amdgcn_mfma_f32_16x16x32_bf16(                      \
            wr[(J) & 7], rw[((J) + ty_) & 3][x2_], acc[t_], 0, 0, 0);           \
      }                                                                         \
    }                                                                           \
  } while (0)

__global__ void __launch_bounds__(256, 4) lambda_main(
    const float* __restrict__ qkv, const float* __restrict__ ascale,
    const float* __restrict__ dshift, const float* __restrict__ cl,
    const short* __restrict__ wfrag, const float* __restrict__ bl,
    float* __restrict__ out) {
    __shared__ unsigned spack[86 * SPW + 8];
    __shared__ float sck[16];

    int vc = blockIdx.x, b = blockIdx.y;
    int tid = threadIdx.x;

    if (tid < 16) sck[tid] = cl[((size_t)b * 16 + tid) * 64 + vc] + bl[tid];

    float av = ascale[64 + vc], dv = dshift[64 + vc];
    const float* vrow = qkv + ((size_t)b * COUT + 80 + vc) * MPIX;
    for (int i = tid; i < 86 * SPW; i += 256) {
        int y = i / SPW, e = i - y * SPW;
        int iy = y - PADH;
        float f0 = 0.f, f1 = 0.f;
        if ((unsigned)iy < 64u) {
            int ix0 = e - PADH, ix1 = e - PADH + 1;
            if ((unsigned)ix0 < 64u) f0 = fmaf(av, vrow[iy * 64 + ix0], dv);
            if ((unsigned)ix1 < 64u) f1 = fmaf(av, vrow[iy * 64 + ix1], dv);
        }
        spack[i] = (unsigned)f2bf(f0) | ((unsigned)f2bf(f1) << 16);
    }
    if (tid < 8) spack[86 * SPW + tid] = 0u;
    __syncthreads();

    int lane = tid & 63;
    int wv = tid >> 6;
    int px = lane & 15;
    int kg = lane >> 4;
    const s16x8* wf = (const s16x8*)wfrag;

    const float* qslab = qkv + (size_t)b * COUT * MPIX;
    float* ob = out + (size_t)b * 256 * MPIX;

    float sck_l[4];
#pragma unroll
    for (int r = 0; r < 4; r++) sck_l[r] = sck[kg * 4 + r];

#pragma unroll 1
    for (int gg = 0; gg < 4; gg++) {
        int y0 = (gg * 4 + wv) * 4;
        const unsigned* base = &spack[y0 * SPW + px + kg * 8];

#pragma unroll 1
        for (int xh = 0; xh < 2; xh++) {
            const unsigned* xbase = base + xh * 32;
            f32x4 acc[8];
#pragma unroll
            for (int t = 0; t < 8; t++) acc[t] = 0.f;

            s16x8 rw[4][2];   // sliding 4-row window, slot = row & 3
            s16x8 wr[8];      // ring-8 weight prefetch, slot = dy & 7
#pragma unroll
            for (int r0 = 0; r0 < 3; r0++) {
                const unsigned* p = xbase + r0 * SPW;
                rw[r0][0] = LD_FRAG(p);
                rw[r0][1] = LD_FRAG(p + 16);
            }
#pragma unroll
            for (int s = 0; s < 7; s++) wr[s] = wf[s * 64 + lane];

#pragma unroll 1
            for (int i8 = 0; i8 < 2; i8++) {
                int dyb = i8 * 8;
                STEP(dyb + 0, 0);
                STEP(dyb + 1, 1);
                STEP(dyb + 2, 2);
                STEP(dyb + 3, 3);
                STEP(dyb + 4, 4);
                STEP(dyb + 5, 5);
                STEP(dyb + 6, 6);
                STEP(dyb + 7, 7);
            }
            STEP(16, 0);
            STEP(17, 1);
            STEP(18, 2);
            STEP(19, 3);
            STEP(20, 4);
            STEP(21, 5);
            STEP(22, 6);

            // epilogue: lane holds pl[kf = kg*4+r][px] for its 8 tiles
#pragma unroll
            for (int t = 0; t < 8; t++) {
                int ty = t >> 1, x2 = t & 1;
                int m0 = (y0 + ty) * 64 + (xh * 2 + x2) * 16;
                float lam[4];
#pragma unroll
                for (int r = 0; r < 4; r++) lam[r] = acc[t][r] + sck_l[r];
                float po[4] = {0.f, 0.f, 0.f, 0.f};
#pragma unroll
                for (int i = 0; i < 16; i++) {
                    float qv = qslab[(size_t)(kg * 16 + i) * MPIX + m0 + px];
                    po[i & 3] = fmaf(qv, lam[i >> 2], po[i & 3]);
                }
#pragma unroll
                for (int n = 0; n < 4; n++) {
                    po[n] += __shfl_xor(po[n], 16);
                    po[n] += __shfl_xor(po[n], 32);
                }
                float sv = (kg == 0) ? po[0] : (kg == 1) ? po[1] : (kg == 2) ? po[2] : po[3];
                ob[(size_t)(kg * 64 + vc) * MPIX + m0 + px] = sv;
            }
        }
    }
}

// ---------------- launch ----------------
extern "C" void kernel_launch(void* const* d_in, const int* in_sizes, int n_in,
                              void* d_out, int out_size, void* d_ws, size_t ws_size,
                              hipStream_t stream) {
    const float* x      = (const float*)d_in[0];
    const float* w_qkv  = (const float*)d_in[1];
    const float* gq     = (const float*)d_in[2];
    const float* bq     = (const float*)d_in[3];
    const float* gv     = (const float*)d_in[4];
    const float* bv     = (const float*)d_in[5];
    const float* wl     = (const float*)d_in[6];
    const float* bl     = (const float*)d_in[7];
    float* out = (float*)d_out;

    float* ws     = (float*)d_ws;
    float* qkv    = ws;                    // 16*144*4096 = 9,437,184
    float* p      = qkv + 9437184;         // 1,048,576
    float* part   = p + 1048576;           // 4,096
    float* ascale = part + 4096;           // 128
    float* dshift = ascale + 128;          // 128
    float* clpart = dshift + 128;          // 262,144
    float* clb    = clpart + 262144;       // 16,384
    short* wfrag  = (short*)(clb + 16384); // 23*64*8 = 11,776 halfs

    gemm_qkv<<<dim3(16, 3, 16), 256, 0, stream>>>(x, w_qkv, qkv);
    stats_partial<<<dim3(128, 16), 256, 0, stream>>>(qkv, part);
    stats_finalize<<<1, 128, 0, stream>>>(part, gq, bq, gv, bv, ascale, dshift);
    softmax_k<<<256, 256, 0, stream>>>(qkv, p);
    cl_partial<<<dim3(16, 16), 256, 0, stream>>>(qkv, p, ascale, dshift, clpart);
    cl_reduce<<<16, 256, 0, stream>>>(clpart, clb);
    bn_q<<<dim3(64, 16), 256, 0, stream>>>(qkv, ascale, dshift);
    wfrag_prep<<<46, 256, 0, stream>>>(wl, wfrag);
    lambda_main<<<dim3(64, 16), 256, 0, stream>>>(qkv, ascale, dshift, clb, wfrag, bl, out);
}